// Round 11
// baseline (2090.866 us; speedup 1.0000x reference)
//
#include <hip/hip_runtime.h>

#define BB 4
#define NN 4096
#define CC 128
#define DD 131          // 3 + 128
#define NPOINT 1024

// IEEE-exact, non-fusable fp32 ops (intrinsics are immune to -ffp-contract)
__device__ __forceinline__ float fmul_(float a, float b) { return __fmul_rn(a, b); }
__device__ __forceinline__ float fadd_(float a, float b) { return __fadd_rn(a, b); }

// ---------------------------------------------------------------------------
// aa[n] = sum_k sq[k], sq = correctly-rounded squares (eager mul op), reduce
// in LLVM loop-vectorizer order (XLA:CPU JIT, fast-math reassoc, VF=8 via
// prefer-vector-width=256, IC=4):
//   4 vector phis over k=0..127:  p[j][l] = sum_{it=0..3} sq[32*it + 8*j + l]
//   linear phi combine:           v = ((p0 + p1) + p2) + p3       (lanewise)
//   horizontal halving tree:      h4[l]=v[l]+v[l+4]; h2[l]=h4[l]+h4[l+2];
//                                 h1 = h2[0]+h2[1]
//   scalar epilogue (k=128..130): ((h1+sq128)+sq129)+sq130
// ---------------------------------------------------------------------------
__device__ float aa_xla_vf8ic4(const float* __restrict__ row) {
    float p[4][8];
#pragma unroll
    for (int j = 0; j < 4; ++j)
#pragma unroll
        for (int l = 0; l < 8; ++l)
            p[j][l] = fmul_(row[8 * j + l], row[8 * j + l]);
#pragma unroll
    for (int it = 1; it < 4; ++it)
#pragma unroll
        for (int j = 0; j < 4; ++j)
#pragma unroll
            for (int l = 0; l < 8; ++l) {
                float x = row[32 * it + 8 * j + l];
                p[j][l] = fadd_(p[j][l], fmul_(x, x));
            }
    float v[8];
#pragma unroll
    for (int l = 0; l < 8; ++l)
        v[l] = fadd_(fadd_(fadd_(p[0][l], p[1][l]), p[2][l]), p[3][l]);
    float h4_0 = fadd_(v[0], v[4]), h4_1 = fadd_(v[1], v[5]);
    float h4_2 = fadd_(v[2], v[6]), h4_3 = fadd_(v[3], v[7]);
    float h2_0 = fadd_(h4_0, h4_2), h2_1 = fadd_(h4_1, h4_3);
    float h1 = fadd_(h2_0, h2_1);
    h1 = fadd_(h1, fmul_(row[128], row[128]));
    h1 = fadd_(h1, fmul_(row[129], row[129]));
    h1 = fadd_(h1, fmul_(row[130], row[130]));
    return h1;
}

// ---------------------------------------------------------------------------
// dist[b][i][j] = fl(fl(aa_i + aa_j) - 2*ab_ij)   (x2 exact, one rounding),
//   ab_ij = ascending-k single-accumulator FMA chain (Eigen gebp order, the
//   ab of the closest-run v2 family).
// 64(i) x 32(j) tile per 256-thread block, 4x2 outputs per thread.
// ---------------------------------------------------------------------------
__global__ __launch_bounds__(256) void dist_kernel(const float* __restrict__ points,
                                                   const float* __restrict__ features,
                                                   float* __restrict__ dist) {
    __shared__ float At[64][132];   // 33,792 B (132: float4-aligned row stride)
    __shared__ float Bt[32][132];   // 16,896 B
    __shared__ float s_aai[64];
    __shared__ float s_aaj[32];

    const int b  = blockIdx.z;
    const int i0 = blockIdx.x * 64;
    const int j0 = blockIdx.y * 32;
    const int tid = threadIdx.x;

    // ---- stage f rows: f[n][k] = k<3 ? points[b,n,k] : features[b,k-3,n]
    {
        const int rA = tid & 63, gA = tid >> 6;     // 4 k-groups over 64 rows
        for (int k = gA; k < DD; k += 4) {
            float v;
            if (k < 3) v = points[((size_t)b * NN + i0 + rA) * 3 + k];
            else       v = features[((size_t)b * CC + (k - 3)) * NN + i0 + rA];
            At[rA][k] = v;
        }
        const int rB = tid & 31, gB = tid >> 5;     // 8 k-groups over 32 rows
        for (int k = gB; k < DD; k += 8) {
            float v;
            if (k < 3) v = points[((size_t)b * NN + j0 + rB) * 3 + k];
            else       v = features[((size_t)b * CC + (k - 3)) * NN + j0 + rB];
            Bt[rB][k] = v;
        }
    }
    __syncthreads();

    // ---- row/col squared norms: XLA:CPU VF8-IC4 vectorized-reduce order
    if (tid < 64)        s_aai[tid]      = aa_xla_vf8ic4(At[tid]);
    else if (tid < 96)   s_aaj[tid - 64] = aa_xla_vf8ic4(Bt[tid - 64]);
    __syncthreads();

    const int tx = tid & 15;        // j pair: j0 + 2*tx + {0,1}
    const int ty = tid >> 4;        // i quad: i0 + 4*ty + {0..3}

    float acc[4][2];
#pragma unroll
    for (int p = 0; p < 4; ++p) { acc[p][0] = 0.f; acc[p][1] = 0.f; }

    // ascending-k FMA chains; float4 LDS reads, in-order scalar fmafs
    for (int kb = 0; kb < 128; kb += 4) {
        float4 a0 = *(const float4*)&At[4 * ty + 0][kb];
        float4 a1 = *(const float4*)&At[4 * ty + 1][kb];
        float4 a2 = *(const float4*)&At[4 * ty + 2][kb];
        float4 a3 = *(const float4*)&At[4 * ty + 3][kb];
        float4 b0 = *(const float4*)&Bt[2 * tx + 0][kb];
        float4 b1 = *(const float4*)&Bt[2 * tx + 1][kb];
        const float4 av[4] = {a0, a1, a2, a3};
        const float4 bv[2] = {b0, b1};
#pragma unroll
        for (int p = 0; p < 4; ++p)
#pragma unroll
            for (int q = 0; q < 2; ++q) {
                float s = acc[p][q];
                s = __builtin_fmaf(av[p].x, bv[q].x, s);
                s = __builtin_fmaf(av[p].y, bv[q].y, s);
                s = __builtin_fmaf(av[p].z, bv[q].z, s);
                s = __builtin_fmaf(av[p].w, bv[q].w, s);
                acc[p][q] = s;
            }
    }
    // tail k = 128..130 (ascending, same chain)
#pragma unroll
    for (int p = 0; p < 4; ++p)
#pragma unroll
        for (int q = 0; q < 2; ++q) {
            float s = acc[p][q];
            s = __builtin_fmaf(At[4 * ty + p][128], Bt[2 * tx + q][128], s);
            s = __builtin_fmaf(At[4 * ty + p][129], Bt[2 * tx + q][129], s);
            s = __builtin_fmaf(At[4 * ty + p][130], Bt[2 * tx + q][130], s);
            acc[p][q] = s;
        }

#pragma unroll
    for (int p = 0; p < 4; ++p) {
        const int i = i0 + 4 * ty + p;
        float2 st;
        st.x = __builtin_fmaf(-2.0f, acc[p][0],
                              fadd_(s_aai[4 * ty + p], s_aaj[2 * tx + 0]));
        st.y = __builtin_fmaf(-2.0f, acc[p][1],
                              fadd_(s_aai[4 * ty + p], s_aaj[2 * tx + 1]));
        *(float2*)&dist[((size_t)b * NN + i) * NN + j0 + 2 * tx] = st;
    }
}

// ---------------------------------------------------------------------------
// Sequential FPS, exact fp32 replication of the reference loop. One
// 1024-thread block per batch; mind in 4 regs/thread; argmax = local(4) ->
// wave64 butterfly -> 16-wave combine via parity-double-buffered LDS +
// butterfly (one barrier/step). Tie-break: lower index (first occurrence).
// ---------------------------------------------------------------------------
__global__ __launch_bounds__(1024) void fps_kernel(const float* __restrict__ dist,
                                                   int* __restrict__ out) {
    const int b = blockIdx.x;
    const int tid = threadIdx.x;
    const int lane = tid & 63;
    const int wave = tid >> 6;
    const float* Dm = dist + (size_t)b * NN * NN;
    const int base = tid * 4;

    __shared__ float s_val[2][16];
    __shared__ int   s_idx[2][16];

    float4 mind = make_float4(1e10f, 1e10f, 1e10f, 1e10f);
    int last = 0;

    for (int k = 0; k < NPOINT; ++k) {
        if (tid == 0) out[b * NPOINT + k] = last;

        float4 d4 = *(const float4*)&Dm[(size_t)last * NN + base];
        mind.x = fminf(mind.x, d4.x);
        mind.y = fminf(mind.y, d4.y);
        mind.z = fminf(mind.z, d4.z);
        mind.w = fminf(mind.w, d4.w);

        float bv = mind.x; int bi = base;
        if (mind.y > bv) { bv = mind.y; bi = base + 1; }
        if (mind.z > bv) { bv = mind.z; bi = base + 2; }
        if (mind.w > bv) { bv = mind.w; bi = base + 3; }

#pragma unroll
        for (int m = 32; m >= 1; m >>= 1) {
            float ov = __shfl_xor(bv, m, 64);
            int   oi = __shfl_xor(bi, m, 64);
            if (ov > bv || (ov == bv && oi < bi)) { bv = ov; bi = oi; }
        }

        const int p = k & 1;
        if (lane == 0) { s_val[p][wave] = bv; s_idx[p][wave] = bi; }
        __syncthreads();

        float v = s_val[p][lane & 15];
        int  ii = s_idx[p][lane & 15];
#pragma unroll
        for (int m = 8; m >= 1; m >>= 1) {
            float ov = __shfl_xor(v, m, 64);
            int   oi = __shfl_xor(ii, m, 64);
            if (ov > v || (ov == v && oi < ii)) { v = ov; ii = oi; }
        }
        last = ii;
    }
}

// ---------------------------------------------------------------------------
extern "C" void kernel_launch(void* const* d_in, const int* in_sizes, int n_in,
                              void* d_out, int out_size, void* d_ws, size_t ws_size,
                              hipStream_t stream) {
    const float* points   = (const float*)d_in[0];
    const float* features = (const float*)d_in[1];
    int* out = (int*)d_out;

    float* dist = (float*)d_ws;   // exactly 256 MiB

    dim3 g(NN / 64, NN / 32, BB);
    dist_kernel<<<g, 256, 0, stream>>>(points, features, dist);

    fps_kernel<<<BB, 1024, 0, stream>>>(dist, out);
}

// Round 12
// 1838.045 us; speedup vs baseline: 1.1375x; 1.1375x over previous
//
#include <hip/hip_runtime.h>

#define BB 4
#define NN 4096
#define CC 128
#define DD 131          // 3 + 128
#define NPOINT 1024

// IEEE-exact, non-fusable fp32 ops (intrinsics are immune to -ffp-contract)
__device__ __forceinline__ float fmul_(float a, float b) { return __fmul_rn(a, b); }
__device__ __forceinline__ float fadd_(float a, float b) { return __fadd_rn(a, b); }

// ---------------------------------------------------------------------------
// aa[n] = sum_k sq[k], sq = correctly-rounded squares, reduce in LLVM
// loop-vectorizer order (XLA:CPU JIT, fast-math reassoc, VF=8, IC=4):
// 4x8-lane phis over k=0..127, linear phi combine, halving tree, 3-elem tail.
// VERIFIED bit-exact vs harness "np" recompute (round 11, absmax 0). DO NOT
// change any arithmetic order in this file's dist pipeline.
// ---------------------------------------------------------------------------
__device__ float aa_xla_vf8ic4(const float* __restrict__ row) {
    float p[4][8];
#pragma unroll
    for (int j = 0; j < 4; ++j)
#pragma unroll
        for (int l = 0; l < 8; ++l)
            p[j][l] = fmul_(row[8 * j + l], row[8 * j + l]);
#pragma unroll
    for (int it = 1; it < 4; ++it)
#pragma unroll
        for (int j = 0; j < 4; ++j)
#pragma unroll
            for (int l = 0; l < 8; ++l) {
                float x = row[32 * it + 8 * j + l];
                p[j][l] = fadd_(p[j][l], fmul_(x, x));
            }
    float v[8];
#pragma unroll
    for (int l = 0; l < 8; ++l)
        v[l] = fadd_(fadd_(fadd_(p[0][l], p[1][l]), p[2][l]), p[3][l]);
    float h4_0 = fadd_(v[0], v[4]), h4_1 = fadd_(v[1], v[5]);
    float h4_2 = fadd_(v[2], v[6]), h4_3 = fadd_(v[3], v[7]);
    float h2_0 = fadd_(h4_0, h4_2), h2_1 = fadd_(h4_1, h4_3);
    float h1 = fadd_(h2_0, h2_1);
    h1 = fadd_(h1, fmul_(row[128], row[128]));
    h1 = fadd_(h1, fmul_(row[129], row[129]));
    h1 = fadd_(h1, fmul_(row[130], row[130]));
    return h1;
}

// ---------------------------------------------------------------------------
// dist[b][i][j] = fl(fl(aa_i + aa_j) - 2*ab_ij)   (x2 exact, one rounding),
//   ab_ij = ascending-k single-accumulator FMA chain (Eigen gebp order).
// 64(i) x 32(j) tile per 256-thread block, 4x2 outputs per thread.
// Bit-exact verified (round 11) — arithmetic order frozen.
// ---------------------------------------------------------------------------
__global__ __launch_bounds__(256) void dist_kernel(const float* __restrict__ points,
                                                   const float* __restrict__ features,
                                                   float* __restrict__ dist) {
    __shared__ float At[64][132];   // 33,792 B (132: float4-aligned row stride)
    __shared__ float Bt[32][132];   // 16,896 B
    __shared__ float s_aai[64];
    __shared__ float s_aaj[32];

    const int b  = blockIdx.z;
    const int i0 = blockIdx.x * 64;
    const int j0 = blockIdx.y * 32;
    const int tid = threadIdx.x;

    // ---- stage f rows: f[n][k] = k<3 ? points[b,n,k] : features[b,k-3,n]
    {
        const int rA = tid & 63, gA = tid >> 6;     // 4 k-groups over 64 rows
        for (int k = gA; k < DD; k += 4) {
            float v;
            if (k < 3) v = points[((size_t)b * NN + i0 + rA) * 3 + k];
            else       v = features[((size_t)b * CC + (k - 3)) * NN + i0 + rA];
            At[rA][k] = v;
        }
        const int rB = tid & 31, gB = tid >> 5;     // 8 k-groups over 32 rows
        for (int k = gB; k < DD; k += 8) {
            float v;
            if (k < 3) v = points[((size_t)b * NN + j0 + rB) * 3 + k];
            else       v = features[((size_t)b * CC + (k - 3)) * NN + j0 + rB];
            Bt[rB][k] = v;
        }
    }
    __syncthreads();

    // ---- row/col squared norms: XLA:CPU VF8-IC4 vectorized-reduce order
    if (tid < 64)        s_aai[tid]      = aa_xla_vf8ic4(At[tid]);
    else if (tid < 96)   s_aaj[tid - 64] = aa_xla_vf8ic4(Bt[tid - 64]);
    __syncthreads();

    const int tx = tid & 15;        // j pair: j0 + 2*tx + {0,1}
    const int ty = tid >> 4;        // i quad: i0 + 4*ty + {0..3}

    float acc[4][2];
#pragma unroll
    for (int p = 0; p < 4; ++p) { acc[p][0] = 0.f; acc[p][1] = 0.f; }

    // ascending-k FMA chains; float4 LDS reads, in-order scalar fmafs
    for (int kb = 0; kb < 128; kb += 4) {
        float4 a0 = *(const float4*)&At[4 * ty + 0][kb];
        float4 a1 = *(const float4*)&At[4 * ty + 1][kb];
        float4 a2 = *(const float4*)&At[4 * ty + 2][kb];
        float4 a3 = *(const float4*)&At[4 * ty + 3][kb];
        float4 b0 = *(const float4*)&Bt[2 * tx + 0][kb];
        float4 b1 = *(const float4*)&Bt[2 * tx + 1][kb];
        const float4 av[4] = {a0, a1, a2, a3};
        const float4 bv[2] = {b0, b1};
#pragma unroll
        for (int p = 0; p < 4; ++p)
#pragma unroll
            for (int q = 0; q < 2; ++q) {
                float s = acc[p][q];
                s = __builtin_fmaf(av[p].x, bv[q].x, s);
                s = __builtin_fmaf(av[p].y, bv[q].y, s);
                s = __builtin_fmaf(av[p].z, bv[q].z, s);
                s = __builtin_fmaf(av[p].w, bv[q].w, s);
                acc[p][q] = s;
            }
    }
    // tail k = 128..130 (ascending, same chain)
#pragma unroll
    for (int p = 0; p < 4; ++p)
#pragma unroll
        for (int q = 0; q < 2; ++q) {
            float s = acc[p][q];
            s = __builtin_fmaf(At[4 * ty + p][128], Bt[2 * tx + q][128], s);
            s = __builtin_fmaf(At[4 * ty + p][129], Bt[2 * tx + q][129], s);
            s = __builtin_fmaf(At[4 * ty + p][130], Bt[2 * tx + q][130], s);
            acc[p][q] = s;
        }

#pragma unroll
    for (int p = 0; p < 4; ++p) {
        const int i = i0 + 4 * ty + p;
        float2 st;
        st.x = __builtin_fmaf(-2.0f, acc[p][0],
                              fadd_(s_aai[4 * ty + p], s_aaj[2 * tx + 0]));
        st.y = __builtin_fmaf(-2.0f, acc[p][1],
                              fadd_(s_aai[4 * ty + p], s_aaj[2 * tx + 1]));
        *(float2*)&dist[((size_t)b * NN + i) * NN + j0 + 2 * tx] = st;
    }
}

// ---------------------------------------------------------------------------
// Sequential FPS — latency-optimized: 256 threads (4 waves) per batch.
// Thread t owns columns {1024*c + 4*t + e : c=0..3, e=0..3} (each load inst
// is a contiguous, coalesced 1KB/wave). mind in 4 float4 registers.
// Per step: 4x float4 loads -> 16-elem register scan (ascending global index,
// strict > = first occurrence) -> 6-step wave64 butterfly -> 4-entry LDS
// exchange (parity double-buffer, ONE barrier) -> 2-step butterfly.
// Tie-break everywhere: lower global index wins (np.argmax semantics).
// ---------------------------------------------------------------------------
__global__ __launch_bounds__(256) void fps_kernel(const float* __restrict__ dist,
                                                  int* __restrict__ out) {
    const int b = blockIdx.x;
    const int tid = threadIdx.x;
    const int lane = tid & 63;
    const int wave = tid >> 6;
    const float* Dm = dist + (size_t)b * NN * NN;

    __shared__ float s_val[2][4];
    __shared__ int   s_idx[2][4];

    float4 mind[4];
#pragma unroll
    for (int c = 0; c < 4; ++c) mind[c] = make_float4(1e10f, 1e10f, 1e10f, 1e10f);
    int last = 0;

    for (int k = 0; k < NPOINT; ++k) {
        if (tid == 0) out[b * NPOINT + k] = last;

        const float* row = Dm + (size_t)last * NN;
        float4 d[4];
#pragma unroll
        for (int c = 0; c < 4; ++c)
            d[c] = *(const float4*)&row[c * 1024 + 4 * tid];

#pragma unroll
        for (int c = 0; c < 4; ++c) {
            mind[c].x = fminf(mind[c].x, d[c].x);
            mind[c].y = fminf(mind[c].y, d[c].y);
            mind[c].z = fminf(mind[c].z, d[c].z);
            mind[c].w = fminf(mind[c].w, d[c].w);
        }

        // local argmax over 16 owned columns, ascending global index order
        float bv = mind[0].x; int bi = 4 * tid;
#pragma unroll
        for (int c = 0; c < 4; ++c) {
            const int base = c * 1024 + 4 * tid;
            const float* m = &mind[c].x;
#pragma unroll
            for (int e = 0; e < 4; ++e) {
                if (c == 0 && e == 0) continue;
                if (m[e] > bv) { bv = m[e]; bi = base + e; }
            }
        }

        // wave64 butterfly argmax (lower index wins ties)
#pragma unroll
        for (int m = 32; m >= 1; m >>= 1) {
            float ov = __shfl_xor(bv, m, 64);
            int   oi = __shfl_xor(bi, m, 64);
            if (ov > bv || (ov == bv && oi < bi)) { bv = ov; bi = oi; }
        }

        // cross-wave combine (4 waves) via parity-double-buffered LDS
        const int p = k & 1;
        if (lane == 0) { s_val[p][wave] = bv; s_idx[p][wave] = bi; }
        __syncthreads();

        float v = s_val[p][lane & 3];
        int  ii = s_idx[p][lane & 3];
#pragma unroll
        for (int m = 2; m >= 1; m >>= 1) {
            float ov = __shfl_xor(v, m, 64);
            int   oi = __shfl_xor(ii, m, 64);
            if (ov > v || (ov == v && oi < ii)) { v = ov; ii = oi; }
        }
        last = ii;
    }
}

// ---------------------------------------------------------------------------
extern "C" void kernel_launch(void* const* d_in, const int* in_sizes, int n_in,
                              void* d_out, int out_size, void* d_ws, size_t ws_size,
                              hipStream_t stream) {
    const float* points   = (const float*)d_in[0];
    const float* features = (const float*)d_in[1];
    int* out = (int*)d_out;

    float* dist = (float*)d_ws;   // exactly 256 MiB

    dim3 g(NN / 64, NN / 32, BB);
    dist_kernel<<<g, 256, 0, stream>>>(points, features, dist);

    fps_kernel<<<BB, 256, 0, stream>>>(dist, out);
}